// Round 2
// baseline (5312.069 us; speedup 1.0000x reference)
//
#include <hip/hip_runtime.h>
#include <math.h>

#define NB    64
#define DIM   256
#define TWOD  512
#define CNTE  1000
#define ETP   65   // eT row pad: bank = (k+n)%32 -> 2-way (free)

__global__ __launch_bounds__(256, 2) void encoder_attn_kernel(
    const int*   __restrict__ nei_rid,   // [B,64]
    const float* __restrict__ nei_e,     // [B,64,256]
    const float* __restrict__ nei_rw,    // [B,64]
    const int*   __restrict__ q_rid,     // [B]
    const float* __restrict__ w_r,       // [1001,256]
    const float* __restrict__ zq_w,      // [1000,256]
    const float* __restrict__ attn_W,    // [512,512] row-major [o][i]
    const float* __restrict__ attn_b,    // [512]
    const float* __restrict__ u_a_w,     // [512]
    const float* __restrict__ u_a_b,     // [1]
    float*       __restrict__ out)       // [B,256]
{
    __shared__ float eT[DIM * ETP];      // e_tr transposed [k][n], 66560 B
    __shared__ float zq_lds[DIM];
    __shared__ float ua_lds[TWOD];
    __shared__ float zpart[TWOD];
    __shared__ float red_ew[256];
    __shared__ float red_ww[256];
    __shared__ float pen[NB];
    __shared__ float attn_lds[NB];
    __shared__ float lg_scratch[4 * NB];

    const int b = blockIdx.x;
    const int t = threadIdx.x;
    const int n = t >> 2;     // neighbor handled in phase 1
    const int q = t & 3;      // k-quarter in phase 1

    // ---- stage z_q and u_a into LDS ----
    const int qr = q_rid[b];
    zq_lds[t]       = zq_w[(size_t)qr * DIM + t];
    ua_lds[t]       = u_a_w[t];
    ua_lds[t + 256] = u_a_w[t + 256];

    // ---- phase 1a: partial dots e.w and w.w (4 threads per neighbor) ----
    const int rid = nei_rid[b * NB + n];
    const float4* e4 = (const float4*)(nei_e + ((size_t)(b * NB + n)) * DIM) + q * 16;
    const float4* w4 = (const float4*)(w_r + (size_t)rid * DIM) + q * 16;
    float sew = 0.f, sww = 0.f;
    #pragma unroll
    for (int j = 0; j < 16; ++j) {
        float4 ev = e4[j], wv = w4[j];
        sew += ev.x * wv.x + ev.y * wv.y + ev.z * wv.z + ev.w * wv.w;
        sww += wv.x * wv.x + wv.y * wv.y + wv.z * wv.z + wv.w * wv.w;
    }
    red_ew[t] = sew;
    red_ww[t] = sww;
    if (q == 0) pen[n] = (rid == CNTE) ? 1e19f : 0.f;
    __syncthreads();

    // ---- phase 1b: projection coefficient, write e_tr transposed ----
    {
        float ew = red_ew[n * 4] + red_ew[n * 4 + 1] + red_ew[n * 4 + 2] + red_ew[n * 4 + 3];
        float ww = red_ww[n * 4] + red_ww[n * 4 + 1] + red_ww[n * 4 + 2] + red_ww[n * 4 + 3];
        float nc   = fmaxf(sqrtf(ww), 1e-12f);
        float coef = ew / (nc * nc);
        float maskf = (rid < CNTE) ? 1.f : 0.f;
        #pragma unroll
        for (int j = 0; j < 16; ++j) {
            float4 ev = e4[j], wv = w4[j];
            int k0 = q * 64 + j * 4;
            eT[(k0 + 0) * ETP + n] = (ev.x - coef * wv.x) * maskf;
            eT[(k0 + 1) * ETP + n] = (ev.y - coef * wv.y) * maskf;
            eT[(k0 + 2) * ETP + n] = (ev.z - coef * wv.z) * maskf;
            eT[(k0 + 3) * ETP + n] = (ev.w - coef * wv.w) * maskf;
        }
    }

    // ---- phase 2: zpart[o] = attn_b[o] + W[o][0:256] . z_q ----
    #pragma unroll
    for (int oo = 0; oo < 2; ++oo) {
        int o = t + oo * 256;
        const float4* wrow = (const float4*)(attn_W + (size_t)o * TWOD);
        const float4* zq4  = (const float4*)zq_lds;
        float acc = attn_b[o];
        #pragma unroll 16
        for (int j = 0; j < 64; ++j) {
            float4 wq = wrow[j];
            float4 zv = zq4[j];
            acc += wq.x * zv.x + wq.y * zv.y + wq.z * zv.z + wq.w * zv.w;
        }
        zpart[o] = acc;
    }
    __syncthreads();   // eT + zpart ready

    // ---- phase 3: GEMM (e-half of W) + tanh + u_a reduction ----
    // W addresses forced wave-uniform via readfirstlane -> scalar s_load path
    // (one load serves all 64 lanes; SMEM issues parallel to VALU).
    const int wv_id = t >> 6;   // wave 0..3 -> o block of 128
    const int lane  = t & 63;   // = neighbor n
    float logit_part = 0.f;
    #pragma unroll 1
    for (int oc = 0; oc < 4; ++oc) {
        const int obase = __builtin_amdgcn_readfirstlane(wv_id * 128 + oc * 32);
        const float* wbase = attn_W + (size_t)obase * TWOD + DIM;  // e-half of row obase
        float acc[32];
        #pragma unroll
        for (int i = 0; i < 32; ++i) acc[i] = 0.f;
        #pragma unroll 1
        for (int kc = 0; kc < DIM; kc += 32) {
            float er[32];
            #pragma unroll
            for (int j = 0; j < 32; ++j) er[j] = eT[(kc + j) * ETP + lane];
            #pragma unroll 4
            for (int oi = 0; oi < 32; ++oi) {
                const float4* wr4 = (const float4*)(wbase + (size_t)oi * TWOD + kc);
                #pragma unroll
                for (int jj = 0; jj < 8; ++jj) {
                    float4 wq = wr4[jj];   // scalar (SGPR) load, broadcast to lanes
                    acc[oi] += wq.x * er[jj * 4 + 0] + wq.y * er[jj * 4 + 1]
                             + wq.z * er[jj * 4 + 2] + wq.w * er[jj * 4 + 3];
                }
            }
        }
        #pragma unroll
        for (int oi = 0; oi < 32; ++oi) {
            int o = obase + oi;
            float h = tanhf(acc[oi] + zpart[o]);
            logit_part += ua_lds[o] * h;
        }
    }
    lg_scratch[wv_id * NB + lane] = logit_part;
    __syncthreads();

    // ---- phase 4: softmax over 64 neighbors (wave 0) ----
    if (t < NB) {
        float lgt = lg_scratch[t] + lg_scratch[NB + t] + lg_scratch[2 * NB + t]
                  + lg_scratch[3 * NB + t] + u_a_b[0] - pen[t];
        float m = lgt;
        #pragma unroll
        for (int off = 32; off > 0; off >>= 1) m = fmaxf(m, __shfl_xor(m, off));
        float ex = __expf(lgt - m);
        float s = ex;
        #pragma unroll
        for (int off = 32; off > 0; off >>= 1) s += __shfl_xor(s, off);
        attn_lds[t] = ex / s + nei_rw[b * NB + t];
    }
    __syncthreads();

    // ---- phase 5: out[b][k] = sum_n attn[n] * e_tr[n][k] ----
    float oacc = 0.f;
    #pragma unroll
    for (int nn = 0; nn < NB; ++nn)
        oacc += attn_lds[nn] * eT[t * ETP + nn];
    out[(size_t)b * DIM + t] = oacc;
}

extern "C" void kernel_launch(void* const* d_in, const int* in_sizes, int n_in,
                              void* d_out, int out_size, void* d_ws, size_t ws_size,
                              hipStream_t stream) {
    const int*   nei_rid = (const int*)  d_in[0];
    const float* nei_e   = (const float*)d_in[1];
    const float* nei_rw  = (const float*)d_in[2];
    const int*   q_rid   = (const int*)  d_in[3];
    const float* w_r     = (const float*)d_in[4];
    const float* zq_w    = (const float*)d_in[5];
    const float* attn_W  = (const float*)d_in[6];
    const float* attn_b  = (const float*)d_in[7];
    const float* u_a_w   = (const float*)d_in[8];
    const float* u_a_b   = (const float*)d_in[9];
    float* out = (float*)d_out;

    const int B = in_sizes[3];   // q_rid length = batch
    hipLaunchKernelGGL(encoder_attn_kernel, dim3(B), dim3(256), 0, stream,
                       nei_rid, nei_e, nei_rw, q_rid, w_r, zq_w,
                       attn_W, attn_b, u_a_w, u_a_b, out);
}

// Round 3
// 625.641 us; speedup vs baseline: 8.4906x; 8.4906x over previous
//
#include <hip/hip_runtime.h>
#include <math.h>

#define NB    64
#define DIM   256
#define TWOD  512
#define CNTE  1000
#define E2S   264          // bf16 row stride for e2 (16B pad -> 2-way banks)
#define LGS   17           // lgred row stride (odd -> conflict-free column sums)

typedef __attribute__((ext_vector_type(8))) short short8;
typedef __attribute__((ext_vector_type(4))) float f32x4;

union U16x8 { uint4 u; short8 s; };

__device__ __forceinline__ unsigned short f2bf(float x) {
    unsigned int u = __float_as_uint(x);
    u += 0x7fffu + ((u >> 16) & 1u);          // round-to-nearest-even
    return (unsigned short)(u >> 16);
}
__device__ __forceinline__ float bf2f(unsigned short h) {
    return __uint_as_float(((unsigned int)h) << 16);
}
__device__ __forceinline__ float tanh_fast(float x) {
    // tanh(x) = 1 - 2/(exp(2x)+1); saturates correctly at +/-inf
    float e = __expf(2.0f * x);
    return 1.0f - 2.0f / (e + 1.0f);
}

// ---- precompute 1: attn_W e-half -> bf16 in MFMA B-fragment order ----
// frag element f = ((ot*8 + kt)*64 + lane)*8 + j  maps to
//   o = ot*16 + (lane&15), k = kt*32 + (lane>>4)*8 + j
__global__ __launch_bounds__(256) void pack_w_kernel(
    const float* __restrict__ attn_W, unsigned short* __restrict__ wbf)
{
    int f = blockIdx.x * 256 + threadIdx.x;           // 0..131071
    int j    = f & 7;
    int lane = (f >> 3) & 63;
    int kt   = (f >> 9) & 7;
    int ot   = f >> 12;                               // 0..31
    int o = ot * 16 + (lane & 15);
    int k = kt * 32 + (lane >> 4) * 8 + j;
    wbf[f] = f2bf(attn_W[(size_t)o * TWOD + DIM + k]);
}

// ---- precompute 2: zpart_all[r][o] = attn_b[o] + W[o][0:256] . zq_w[r] ----
__global__ __launch_bounds__(256) void zpart_kernel(
    const float* __restrict__ zq_w, const float* __restrict__ attn_W,
    const float* __restrict__ attn_b, float* __restrict__ zp_all)
{
    __shared__ float zq[DIM];
    const int r = blockIdx.x, t = threadIdx.x;
    zq[t] = zq_w[(size_t)r * DIM + t];
    __syncthreads();
    #pragma unroll
    for (int oo = 0; oo < 2; ++oo) {
        int o = t + oo * 256;
        const float4* w4 = (const float4*)(attn_W + (size_t)o * TWOD);
        const float4* z4 = (const float4*)zq;
        float acc = attn_b[o];
        #pragma unroll 16
        for (int j = 0; j < 64; ++j) {
            float4 wv = w4[j], zv = z4[j];
            acc += wv.x * zv.x + wv.y * zv.y + wv.z * zv.z + wv.w * zv.w;
        }
        zp_all[(size_t)r * TWOD + o] = acc;
    }
}

// ---- main fused kernel: one block per batch element ----
__global__ __launch_bounds__(256, 2) void encoder_attn_kernel(
    const int*   __restrict__ nei_rid,   // [B,64]
    const float* __restrict__ nei_e,     // [B,64,256]
    const float* __restrict__ nei_rw,    // [B,64]
    const int*   __restrict__ q_rid,     // [B]
    const float* __restrict__ w_r,       // [1001,256]
    const float* __restrict__ u_a_w,     // [512]
    const float* __restrict__ u_a_b,     // [1]
    const unsigned short* __restrict__ wbf,   // [32][8][64][8] bf16 B-frags
    const float* __restrict__ zp_all,    // [1000][512]
    float*       __restrict__ out)       // [B,256]
{
    __shared__ __align__(16) unsigned short e2[NB * E2S];  // e_tr bf16, 33792 B
    __shared__ float2 zpua[TWOD];                          // (zpart, u_a) 4 KB
    __shared__ float  red_a[256];
    __shared__ float  red_b[256];
    __shared__ float  lgred[4 * NB * LGS];                 // 17408 B
    __shared__ float  pen[NB];
    __shared__ float  attn_lds[NB];

    const int b = blockIdx.x;
    const int t = threadIdx.x;

    // stage (zpart, u_a) pairs
    const int qr = q_rid[b];
    zpua[t]       = make_float2(zp_all[(size_t)qr * TWOD + t],       u_a_w[t]);
    zpua[t + 256] = make_float2(zp_all[(size_t)qr * TWOD + t + 256], u_a_w[t + 256]);

    // ---- phase 1a: partial dots e.w and w.w (4 threads per neighbor) ----
    const int n = t >> 2, q = t & 3;
    const int rid = nei_rid[b * NB + n];
    const float4* e4 = (const float4*)(nei_e + ((size_t)(b * NB + n)) * DIM) + q * 16;
    const float4* w4 = (const float4*)(w_r + (size_t)rid * DIM) + q * 16;
    float sew = 0.f, sww = 0.f;
    #pragma unroll
    for (int j = 0; j < 16; ++j) {
        float4 ev = e4[j], wv = w4[j];
        sew += ev.x * wv.x + ev.y * wv.y + ev.z * wv.z + ev.w * wv.w;
        sww += wv.x * wv.x + wv.y * wv.y + wv.z * wv.z + wv.w * wv.w;
    }
    red_a[t] = sew;
    red_b[t] = sww;
    if (q == 0) pen[n] = (rid == CNTE) ? 1e19f : 0.f;
    __syncthreads();

    // ---- phase 1b: projection, write e_tr as bf16 into e2 ----
    {
        float ew = red_a[n * 4] + red_a[n * 4 + 1] + red_a[n * 4 + 2] + red_a[n * 4 + 3];
        float ww = red_b[n * 4] + red_b[n * 4 + 1] + red_b[n * 4 + 2] + red_b[n * 4 + 3];
        float nc   = fmaxf(sqrtf(ww), 1e-12f);
        float coef = ew / (nc * nc);
        float maskf = (rid < CNTE) ? 1.f : 0.f;
        unsigned short* e2row = e2 + n * E2S + q * 64;
        #pragma unroll
        for (int jj = 0; jj < 8; ++jj) {
            float4 ev0 = e4[jj * 2],     wv0 = w4[jj * 2];
            float4 ev1 = e4[jj * 2 + 1], wv1 = w4[jj * 2 + 1];
            uint4 pk;
            pk.x = (unsigned int)f2bf((ev0.x - coef * wv0.x) * maskf)
                 | ((unsigned int)f2bf((ev0.y - coef * wv0.y) * maskf) << 16);
            pk.y = (unsigned int)f2bf((ev0.z - coef * wv0.z) * maskf)
                 | ((unsigned int)f2bf((ev0.w - coef * wv0.w) * maskf) << 16);
            pk.z = (unsigned int)f2bf((ev1.x - coef * wv1.x) * maskf)
                 | ((unsigned int)f2bf((ev1.y - coef * wv1.y) * maskf) << 16);
            pk.w = (unsigned int)f2bf((ev1.z - coef * wv1.z) * maskf)
                 | ((unsigned int)f2bf((ev1.w - coef * wv1.w) * maskf) << 16);
            *(uint4*)(e2row + jj * 8) = pk;
        }
    }
    __syncthreads();

    // ---- phase 3: MFMA GEMM  S[n,o] = sum_k e_tr[n,k] * W[o,256+k] ----
    const int wv  = t >> 6;          // wave -> o range [wv*128, wv*128+128)
    const int lane = t & 63;
    const int l15 = lane & 15, lq = lane >> 4;

    // A fragments: a[mt][kt], lane holds A[mt*16+l15][kt*32+lq*8+j]
    short8 afrag[4][8];
    #pragma unroll
    for (int mt = 0; mt < 4; ++mt)
        #pragma unroll
        for (int kt = 0; kt < 8; ++kt) {
            const unsigned short* p = e2 + (mt * 16 + l15) * E2S + kt * 32 + lq * 8;
            U16x8 u; u.u = *(const uint4*)p;
            afrag[mt][kt] = u.s;
        }

    f32x4 lpv[4];
    #pragma unroll
    for (int mt = 0; mt < 4; ++mt) lpv[mt] = (f32x4){0.f, 0.f, 0.f, 0.f};

    #pragma unroll 1
    for (int ot = 0; ot < 8; ++ot) {
        const int otg = wv * 8 + ot;
        short8 bfrag[8];
        #pragma unroll
        for (int kt = 0; kt < 8; ++kt) {
            U16x8 u; u.u = ((const uint4*)wbf)[(otg * 8 + kt) * 64 + lane];
            bfrag[kt] = u.s;
        }
        f32x4 acc[4];
        #pragma unroll
        for (int mt = 0; mt < 4; ++mt) acc[mt] = (f32x4){0.f, 0.f, 0.f, 0.f};
        #pragma unroll
        for (int kt = 0; kt < 8; ++kt)
            #pragma unroll
            for (int mt = 0; mt < 4; ++mt)
                acc[mt] = __builtin_amdgcn_mfma_f32_16x16x32_bf16(
                              afrag[mt][kt], bfrag[kt], acc[mt], 0, 0, 0);
        // epilogue: o is fixed per lane within this o-tile
        float2 zu = zpua[otg * 16 + l15];
        #pragma unroll
        for (int mt = 0; mt < 4; ++mt)
            #pragma unroll
            for (int r = 0; r < 4; ++r) {
                float h = tanh_fast(acc[mt][r] + zu.x);
                lpv[mt][r] += zu.y * h;
            }
    }
    // scatter per-lane logit partials: row n = mt*16 + lq*4 + r, col-slot l15
    #pragma unroll
    for (int mt = 0; mt < 4; ++mt)
        #pragma unroll
        for (int r = 0; r < 4; ++r) {
            int row = mt * 16 + lq * 4 + r;
            lgred[(wv * NB + row) * LGS + l15] = lpv[mt][r];
        }
    __syncthreads();

    // ---- phase 4a: sum 16 col-slots per (wave, row) ----
    {
        int nn = t & 63, wq = t >> 6;
        const float* lr = lgred + (wq * NB + nn) * LGS;
        float s = 0.f;
        #pragma unroll
        for (int i = 0; i < 16; ++i) s += lr[i];
        red_a[t] = s;
    }
    __syncthreads();

    // ---- phase 4b: softmax over 64 neighbors (wave 0) ----
    if (t < NB) {
        float lgt = red_a[t] + red_a[64 + t] + red_a[128 + t] + red_a[192 + t]
                  + u_a_b[0] - pen[t];
        float m = lgt;
        #pragma unroll
        for (int off = 32; off > 0; off >>= 1) m = fmaxf(m, __shfl_xor(m, off));
        float ex = __expf(lgt - m);
        float s = ex;
        #pragma unroll
        for (int off = 32; off > 0; off >>= 1) s += __shfl_xor(s, off);
        attn_lds[t] = ex / s + nei_rw[b * NB + t];
    }
    __syncthreads();

    // ---- phase 5: out[b][k] = sum_n attn[n] * e_tr[n][k] (bf16 read) ----
    float oacc = 0.f;
    #pragma unroll 8
    for (int nn = 0; nn < NB; ++nn)
        oacc += attn_lds[nn] * bf2f(e2[nn * E2S + t]);
    out[(size_t)b * DIM + t] = oacc;
}

extern "C" void kernel_launch(void* const* d_in, const int* in_sizes, int n_in,
                              void* d_out, int out_size, void* d_ws, size_t ws_size,
                              hipStream_t stream) {
    const int*   nei_rid = (const int*)  d_in[0];
    const float* nei_e   = (const float*)d_in[1];
    const float* nei_rw  = (const float*)d_in[2];
    const int*   q_rid   = (const int*)  d_in[3];
    const float* w_r     = (const float*)d_in[4];
    const float* zq_w    = (const float*)d_in[5];
    const float* attn_W  = (const float*)d_in[6];
    const float* attn_b  = (const float*)d_in[7];
    const float* u_a_w   = (const float*)d_in[8];
    const float* u_a_b   = (const float*)d_in[9];
    float* out = (float*)d_out;

    const int B    = in_sizes[3];            // 4096
    const int N_ZQ = in_sizes[5] / DIM;      // 1000

    unsigned short* wbf    = (unsigned short*)d_ws;            // 256 KB
    float*          zp_all = (float*)((char*)d_ws + 512 * 1024); // 1000*512*4 = 2 MB

    hipLaunchKernelGGL(pack_w_kernel, dim3(512), dim3(256), 0, stream, attn_W, wbf);
    hipLaunchKernelGGL(zpart_kernel, dim3(N_ZQ), dim3(256), 0, stream,
                       zq_w, attn_W, attn_b, zp_all);
    hipLaunchKernelGGL(encoder_attn_kernel, dim3(B), dim3(256), 0, stream,
                       nei_rid, nei_e, nei_rw, q_rid, w_r,
                       u_a_w, u_a_b, wbf, zp_all, out);
}

// Round 4
// 525.352 us; speedup vs baseline: 10.1114x; 1.1909x over previous
//
#include <hip/hip_runtime.h>
#include <math.h>

#define NB    64
#define DIM   256
#define TWOD  512
#define CNTE  1000
#define E2S   264          // bf16 row stride, 528 B (16B-aligned; A-read conflicts minor per R3 counter)

typedef __attribute__((ext_vector_type(8))) short short8;
typedef __attribute__((ext_vector_type(4))) float f32x4;

union U16x8 { uint4 u; short8 s; };

__device__ __forceinline__ unsigned short f2bf(float x) {
    unsigned int u = __float_as_uint(x);
    u += 0x7fffu + ((u >> 16) & 1u);          // round-to-nearest-even
    return (unsigned short)(u >> 16);
}
__device__ __forceinline__ float bf2f(unsigned short h) {
    return __uint_as_float(((unsigned int)h) << 16);
}
__device__ __forceinline__ float tanh_fast(float x) {
    float e = __expf(2.0f * x);
    return 1.0f - 2.0f / (e + 1.0f);
}

// ---- precompute: FULL attn_W (512x512) -> bf16 in MFMA B-fragment order ----
// frag f = ((ot*16 + kt)*64 + lane)*8 + j  ->  o = ot*16 + (lane&15),
// k = kt*32 + (lane>>4)*8 + j   (k<256 = z-half, k>=256 = e-half)
__global__ __launch_bounds__(256) void pack_w_kernel(
    const float* __restrict__ attn_W, unsigned short* __restrict__ wbf)
{
    int f = blockIdx.x * 256 + threadIdx.x;           // 0..262143
    int j    = f & 7;
    int lane = (f >> 3) & 63;
    int kt   = (f >> 9) & 15;
    int ot   = f >> 13;                               // 0..31
    int o = ot * 16 + (lane & 15);
    int k = kt * 32 + (lane >> 4) * 8 + j;
    wbf[f] = f2bf(attn_W[(size_t)o * TWOD + k]);
}

// ---- main fused kernel: one block per batch element ----
__global__ __launch_bounds__(256, 2) void encoder_attn_kernel(
    const int*   __restrict__ nei_rid,   // [B,64]
    const float* __restrict__ nei_e,     // [B,64,256]
    const float* __restrict__ nei_rw,    // [B,64]
    const int*   __restrict__ q_rid,     // [B]
    const float* __restrict__ w_r,       // [1001,256]
    const float* __restrict__ zq_w,      // [1000,256]
    const float* __restrict__ attn_b,    // [512]
    const float* __restrict__ u_a_w,     // [512]
    const float* __restrict__ u_a_b,     // [1]
    const unsigned short* __restrict__ wbf,   // [32][16][64][8] bf16 B-frags (K=512)
    float*       __restrict__ out)       // [B,256]
{
    __shared__ __align__(16) unsigned short e2[NB * E2S];  // e_tr bf16, 33792 B
    __shared__ __align__(16) unsigned short zq2[DIM];      // zq bf16, 512 B
    __shared__ float2 bua[TWOD];                           // (attn_b, u_a) 4 KB
    __shared__ float  red_a[256];
    __shared__ float  pen[NB];
    __shared__ float  attn_lds[NB];

    const int b = blockIdx.x;
    const int t = threadIdx.x;

    // stage (attn_b, u_a) and zq (bf16)
    const int qr = q_rid[b];
    bua[t]       = make_float2(attn_b[t],       u_a_w[t]);
    bua[t + 256] = make_float2(attn_b[t + 256], u_a_w[t + 256]);
    zq2[t] = f2bf(zq_w[(size_t)qr * DIM + t]);

    // ---- phase 1: TransH projection (4 threads per neighbor, regs held) ----
    const int n = t >> 2, q = t & 3;
    const int rid = nei_rid[b * NB + n];
    const float4* e4 = (const float4*)(nei_e + ((size_t)(b * NB + n)) * DIM) + q * 16;
    const float4* w4 = (const float4*)(w_r + (size_t)rid * DIM) + q * 16;
    {
        float4 ev[16], wv[16];
        float sew = 0.f, sww = 0.f;
        #pragma unroll
        for (int j = 0; j < 16; ++j) {
            ev[j] = e4[j]; wv[j] = w4[j];
            sew += ev[j].x * wv[j].x + ev[j].y * wv[j].y + ev[j].z * wv[j].z + ev[j].w * wv[j].w;
            sww += wv[j].x * wv[j].x + wv[j].y * wv[j].y + wv[j].z * wv[j].z + wv[j].w * wv[j].w;
        }
        // 4-lane reduction via shuffles (partners are adjacent lanes)
        sew += __shfl_xor(sew, 1); sew += __shfl_xor(sew, 2);
        sww += __shfl_xor(sww, 1); sww += __shfl_xor(sww, 2);
        float nc   = fmaxf(sqrtf(sww), 1e-12f);
        float coef = sew / (nc * nc);
        float maskf = (rid < CNTE) ? 1.f : 0.f;
        if (q == 0) pen[n] = (rid == CNTE) ? 1e19f : 0.f;
        unsigned short* e2row = e2 + n * E2S + q * 64;
        #pragma unroll
        for (int jj = 0; jj < 8; ++jj) {
            float4 e0 = ev[jj * 2],     w0 = wv[jj * 2];
            float4 e1 = ev[jj * 2 + 1], w1 = wv[jj * 2 + 1];
            uint4 pk;
            pk.x = (unsigned int)f2bf((e0.x - coef * w0.x) * maskf)
                 | ((unsigned int)f2bf((e0.y - coef * w0.y) * maskf) << 16);
            pk.y = (unsigned int)f2bf((e0.z - coef * w0.z) * maskf)
                 | ((unsigned int)f2bf((e0.w - coef * w0.w) * maskf) << 16);
            pk.z = (unsigned int)f2bf((e1.x - coef * w1.x) * maskf)
                 | ((unsigned int)f2bf((e1.y - coef * w1.y) * maskf) << 16);
            pk.w = (unsigned int)f2bf((e1.z - coef * w1.z) * maskf)
                 | ((unsigned int)f2bf((e1.w - coef * w1.w) * maskf) << 16);
            *(uint4*)(e2row + jj * 8) = pk;
        }
    }
    __syncthreads();   // e2 + zq2 + bua ready

    // ---- phase 3: MFMA GEMM, K=512: A = [zq (broadcast rows) | e_tr] ----
    const int wv_id = t >> 6;        // wave -> o range [wv_id*128, +128)
    const int lane  = t & 63;
    const int l15 = lane & 15, lq = lane >> 4;

    // A e-half fragments hoisted (128 regs; spills to AGPR side of unified file)
    short8 afrag[4][8];
    #pragma unroll
    for (int mt = 0; mt < 4; ++mt)
        #pragma unroll
        for (int kt = 0; kt < 8; ++kt) {
            const unsigned short* p = e2 + (mt * 16 + l15) * E2S + kt * 32 + lq * 8;
            U16x8 u; u.u = *(const uint4*)p;
            afrag[mt][kt] = u.s;
        }

    f32x4 lpv[4];
    #pragma unroll
    for (int mt = 0; mt < 4; ++mt) lpv[mt] = (f32x4){0.f, 0.f, 0.f, 0.f};

    #pragma unroll 1
    for (int ot = 0; ot < 8; ++ot) {
        const int otg = wv_id * 8 + ot;
        const uint4* wp = (const uint4*)wbf + (size_t)(otg * 16) * 64 + lane;
        short8 bz[8], be[8];
        #pragma unroll
        for (int kt = 0; kt < 8; ++kt) { U16x8 u; u.u = wp[kt * 64]; bz[kt] = u.s; }
        #pragma unroll
        for (int kt = 0; kt < 8; ++kt) { U16x8 u; u.u = wp[(kt + 8) * 64]; be[kt] = u.s; }

        // z-half: rows identical -> one acc chain shared by all row-tiles
        f32x4 accz = (f32x4){0.f, 0.f, 0.f, 0.f};
        #pragma unroll
        for (int kt = 0; kt < 8; ++kt) {
            U16x8 u; u.u = *(const uint4*)(zq2 + kt * 32 + lq * 8);  // broadcast read
            accz = __builtin_amdgcn_mfma_f32_16x16x32_bf16(u.s, bz[kt], accz, 0, 0, 0);
        }
        f32x4 acc[4];
        #pragma unroll
        for (int mt = 0; mt < 4; ++mt) acc[mt] = accz;
        #pragma unroll
        for (int kt = 0; kt < 8; ++kt)
            #pragma unroll
            for (int mt = 0; mt < 4; ++mt)
                acc[mt] = __builtin_amdgcn_mfma_f32_16x16x32_bf16(
                              afrag[mt][kt], be[kt], acc[mt], 0, 0, 0);

        float2 zu = bua[otg * 16 + l15];   // (bias, u_a) for this lane's o
        #pragma unroll
        for (int mt = 0; mt < 4; ++mt)
            #pragma unroll
            for (int r = 0; r < 4; ++r) {
                float h = tanh_fast(acc[mt][r] + zu.x);
                lpv[mt][r] += zu.y * h;
            }
    }

    // ---- logit reduction over l15 (16 col-slots) via shuffles ----
    #pragma unroll
    for (int mt = 0; mt < 4; ++mt)
        #pragma unroll
        for (int r = 0; r < 4; ++r) {
            float v = lpv[mt][r];
            v += __shfl_xor(v, 1); v += __shfl_xor(v, 2);
            v += __shfl_xor(v, 4); v += __shfl_xor(v, 8);
            if (l15 == 0) red_a[wv_id * 64 + mt * 16 + lq * 4 + r] = v;
        }
    __syncthreads();

    // ---- phase 4: softmax over 64 neighbors (wave 0) ----
    if (t < NB) {
        float lgt = red_a[t] + red_a[64 + t] + red_a[128 + t] + red_a[192 + t]
                  + u_a_b[0] - pen[t];
        float m = lgt;
        #pragma unroll
        for (int off = 32; off > 0; off >>= 1) m = fmaxf(m, __shfl_xor(m, off));
        float ex = __expf(lgt - m);
        float s = ex;
        #pragma unroll
        for (int off = 32; off > 0; off >>= 1) s += __shfl_xor(s, off);
        attn_lds[t] = ex / s + nei_rw[b * NB + t];
    }
    __syncthreads();

    // ---- phase 5: out[b][k] = sum_n attn[n] * e_tr[n][k] ----
    float oacc = 0.f;
    #pragma unroll 8
    for (int nn = 0; nn < NB; ++nn)
        oacc += attn_lds[nn] * bf2f(e2[nn * E2S + t]);
    out[(size_t)b * DIM + t] = oacc;
}

extern "C" void kernel_launch(void* const* d_in, const int* in_sizes, int n_in,
                              void* d_out, int out_size, void* d_ws, size_t ws_size,
                              hipStream_t stream) {
    const int*   nei_rid = (const int*)  d_in[0];
    const float* nei_e   = (const float*)d_in[1];
    const float* nei_rw  = (const float*)d_in[2];
    const int*   q_rid   = (const int*)  d_in[3];
    const float* w_r     = (const float*)d_in[4];
    const float* zq_w    = (const float*)d_in[5];
    const float* attn_W  = (const float*)d_in[6];
    const float* attn_b  = (const float*)d_in[7];
    const float* u_a_w   = (const float*)d_in[8];
    const float* u_a_b   = (const float*)d_in[9];
    float* out = (float*)d_out;

    const int B = in_sizes[3];               // 4096

    unsigned short* wbf = (unsigned short*)d_ws;   // 512 KB (K=512 pack)

    hipLaunchKernelGGL(pack_w_kernel, dim3(1024), dim3(256), 0, stream, attn_W, wbf);
    hipLaunchKernelGGL(encoder_attn_kernel, dim3(B), dim3(256), 0, stream,
                       nei_rid, nei_e, nei_rw, q_rid, w_r, zq_w,
                       attn_b, u_a_w, u_a_b, wbf, out);
}